// Round 2
// baseline (303.222 us; speedup 1.0000x reference)
//
#include <hip/hip_runtime.h>
#include <math.h>

// CSConv: grouped conv (groups=256, Cout=512, K=3, pad=1) + bias + BN(inference) + SiLU
// x: (16, 256, 80, 80) f32; w: (512, 1, 3, 3); per-channel b/gamma/beta/mean/var (512)
// out: (16, 512, 80, 80) f32. Output channel co uses input channel co>>1.
// One block per (b, g): stage the 80x80 plane into a zero-padded 82x82 LDS tile,
// each thread computes both output channels for its pixel-quads (float4 I/O).

#define CS_B    16
#define CS_CIN  256
#define CS_COUT 512
#define CS_H    80
#define CS_W    80
#define CS_HP   82
#define CS_WP   82
#define BN_EPS  1e-5f
#define NQ      (CS_H * CS_W / 4)   // 1600 quads per plane

__global__ __launch_bounds__(256) void csconv_kernel(
    const float* __restrict__ x,
    const float* __restrict__ wgt,
    const float* __restrict__ bias,
    const float* __restrict__ gamma,
    const float* __restrict__ beta,
    const float* __restrict__ mean,
    const float* __restrict__ var,
    float* __restrict__ out)
{
    const int blk = blockIdx.x;      // b * 256 + g
    const int g   = blk & (CS_CIN - 1);
    const int b   = blk >> 8;
    const int tid = threadIdx.x;

    __shared__ float tile[CS_HP][CS_WP];

    // Zero the whole padded tile (halo), then stage the interior with float4 loads.
    float* tflat = &tile[0][0];
    for (int i = tid; i < CS_HP * CS_WP; i += 256) tflat[i] = 0.0f;
    __syncthreads();

    const float* xp = x + (size_t)(b * CS_CIN + g) * (CS_H * CS_W);
    const float4* xp4 = (const float4*)xp;
    for (int q = tid; q < NQ; q += 256) {
        int r = q / (CS_W / 4);            // 20 quads per row
        int c4 = (q - r * (CS_W / 4)) * 4;
        float4 v = xp4[q];
        tile[r + 1][c4 + 1] = v.x;
        tile[r + 1][c4 + 2] = v.y;
        tile[r + 1][c4 + 3] = v.z;
        tile[r + 1][c4 + 4] = v.w;
    }
    __syncthreads();

    const int co0 = 2 * g;
    const int co1 = co0 + 1;

    float k0[9], k1[9];
#pragma unroll
    for (int t = 0; t < 9; ++t) {
        k0[t] = wgt[co0 * 9 + t];
        k1[t] = wgt[co1 * 9 + t];
    }
    // Fold bias into BN shift: y = conv*s + (bias*s + beta - mean*s)
    const float s0 = gamma[co0] * rsqrtf(var[co0] + BN_EPS);
    const float s1 = gamma[co1] * rsqrtf(var[co1] + BN_EPS);
    const float t0 = beta[co0] + (bias[co0] - mean[co0]) * s0;
    const float t1 = beta[co1] + (bias[co1] - mean[co1]) * s1;

    float* op0 = out + ((size_t)b * CS_COUT + co0) * (CS_H * CS_W);
    float* op1 = op0 + CS_H * CS_W;

    for (int q = tid; q < NQ; q += 256) {
        int r = q / (CS_W / 4);
        int c4 = (q - r * (CS_W / 4)) * 4;

        float acc0[4] = {0.f, 0.f, 0.f, 0.f};
        float acc1[4] = {0.f, 0.f, 0.f, 0.f};
#pragma unroll
        for (int kh = 0; kh < 3; ++kh) {
            // 6 contiguous tile values cover the 3-tap window of 4 pixels
            float v0 = tile[r + kh][c4 + 0];
            float v1 = tile[r + kh][c4 + 1];
            float v2 = tile[r + kh][c4 + 2];
            float v3 = tile[r + kh][c4 + 3];
            float v4 = tile[r + kh][c4 + 4];
            float v5 = tile[r + kh][c4 + 5];
            float w00 = k0[kh * 3 + 0], w01 = k0[kh * 3 + 1], w02 = k0[kh * 3 + 2];
            float w10 = k1[kh * 3 + 0], w11 = k1[kh * 3 + 1], w12 = k1[kh * 3 + 2];
            acc0[0] = fmaf(v0, w00, fmaf(v1, w01, fmaf(v2, w02, acc0[0])));
            acc0[1] = fmaf(v1, w00, fmaf(v2, w01, fmaf(v3, w02, acc0[1])));
            acc0[2] = fmaf(v2, w00, fmaf(v3, w01, fmaf(v4, w02, acc0[2])));
            acc0[3] = fmaf(v3, w00, fmaf(v4, w01, fmaf(v5, w02, acc0[3])));
            acc1[0] = fmaf(v0, w10, fmaf(v1, w11, fmaf(v2, w12, acc1[0])));
            acc1[1] = fmaf(v1, w10, fmaf(v2, w11, fmaf(v3, w12, acc1[1])));
            acc1[2] = fmaf(v2, w10, fmaf(v3, w11, fmaf(v4, w12, acc1[2])));
            acc1[3] = fmaf(v3, w10, fmaf(v4, w11, fmaf(v5, w12, acc1[3])));
        }

        float4 y0, y1;
        float* y0p = &y0.x;
        float* y1p = &y1.x;
#pragma unroll
        for (int j = 0; j < 4; ++j) {
            float a0 = fmaf(acc0[j], s0, t0);
            float a1 = fmaf(acc1[j], s1, t1);
            y0p[j] = a0 / (1.0f + expf(-a0));
            y1p[j] = a1 / (1.0f + expf(-a1));
        }
        ((float4*)op0)[q] = y0;
        ((float4*)op1)[q] = y1;
    }
}

extern "C" void kernel_launch(void* const* d_in, const int* in_sizes, int n_in,
                              void* d_out, int out_size, void* d_ws, size_t ws_size,
                              hipStream_t stream) {
    const float* x     = (const float*)d_in[0];
    const float* wgt   = (const float*)d_in[1];
    const float* bias  = (const float*)d_in[2];
    const float* gamma = (const float*)d_in[3];
    const float* beta  = (const float*)d_in[4];
    const float* mean  = (const float*)d_in[5];
    const float* var   = (const float*)d_in[6];
    float* out = (float*)d_out;

    dim3 grid(CS_B * CS_CIN);
    dim3 block(256);
    csconv_kernel<<<grid, block, 0, stream>>>(x, wgt, bias, gamma, beta, mean, var, out);
}